// Round 6
// baseline (385.810 us; speedup 1.0000x reference)
//
#include <hip/hip_runtime.h>
#include <math.h>

// R0-R5: infra failures (5x acquisition timeout, 1x container failure) —
// kernel never executed. Architecture: sparse CSR fixpoint in LDS (<=1152
// edges/batch, hard bound 4*SSZ from top2+transpose); no dense W. Audited vs
// JAX reference 3x (R2,R3,R5): index maps, tie semantics, Wsg*mask fixpoint,
// deg=mask-count, exact +/-0.0 sums, full write coverage, ws bounds guard.

#define BATCH 64
#define NTOK 577
#define PTOK 576
#define DIM 768
#define DENS 288        // density = P*KEEP_RATIO
#define SSZ 288         // S = P - density
#define GSZ 144         // G = S*GROUP_RATIO
#define MAXE 1152       // hard bound: 4*SSZ directed edges per batch
#define AB_STRIDE (NTOK*PTOK)    // attention batch stride
#define TK_BSTRIDE (NTOK*DIM)    // tk batch stride
#define OUT_ROWS 433             // 1 + DENS + GSZ
#define R_COLS 432               // DENS + GSZ
#define OUT_TOK_TOTAL ((size_t)BATCH*OUT_ROWS*DIM)
#define WS_NEEDED ((size_t)995584)

// ---------------------------------------------------------------------------
// Kernel 1: per-batch stable descending argsort of cls_attn (= attention row 0)
// rank = #{j: v[j]>v[i]} + #{j<i: v[j]==v[i]}  (matches stable argsort(-v))
// ---------------------------------------------------------------------------
__global__ __launch_bounds__(PTOK) void k_sort(const float* __restrict__ attn,
                                               int* __restrict__ order) {
  __shared__ float v[PTOK];
  const int b = blockIdx.x;
  const int t = threadIdx.x;
  v[t] = attn[(size_t)b * AB_STRIDE + t];
  __syncthreads();
  const float vi = v[t];
  int rank = 0;
  #pragma unroll 4
  for (int j = 0; j < PTOK; ++j) {
    const float vj = v[j];
    rank += ((vj > vi) || (vj == vi && j < t)) ? 1 : 0;
  }
  order[b * PTOK + rank] = t;
}

// ---------------------------------------------------------------------------
// Kernel 2: top-2 per row of adj (zero diag), jax.lax.top_k tie semantics
// (value desc, index asc). One wave per row.
// adj[b,i,j] = attention[b, 1+order[b,288+i], order[b,288+j]]
// ---------------------------------------------------------------------------
__global__ __launch_bounds__(256) void k_top2(const float* __restrict__ attn,
                                              const int* __restrict__ order,
                                              int* __restrict__ t2a,
                                              int* __restrict__ t2b) {
  const int rowg = blockIdx.x * 4 + (threadIdx.x >> 6);
  const int lane = threadIdx.x & 63;
  const int b = rowg / SSZ;
  const int i = rowg - b * SSZ;
  const int* ordb = order + b * PTOK + DENS;
  const float* arow = attn + (size_t)b * AB_STRIDE + (size_t)(1 + ordb[i]) * PTOK;

  float v1 = -1.0f, v2 = -1.0f;          // adj values >= 0
  int i1 = 1 << 30, i2 = 1 << 30;
  for (int j = lane; j < SSZ; j += 64) {
    const float v = (j == i) ? 0.0f : arow[ordb[j]];
    if (v > v1) { v2 = v1; i2 = i1; v1 = v; i1 = j; }
    else if (v > v2) { v2 = v; i2 = j; }
  }
  for (int m = 1; m < 64; m <<= 1) {
    const float o1 = __shfl_xor(v1, m); const int oi1 = __shfl_xor(i1, m);
    const float o2 = __shfl_xor(v2, m); const int oi2 = __shfl_xor(i2, m);
    const bool aFirst = (v1 > o1) || (v1 == o1 && i1 < oi1);
    float nv1, nv2; int ni1, ni2;
    if (aFirst) {
      nv1 = v1; ni1 = i1;
      const bool s = (v2 > o1) || (v2 == o1 && i2 < oi1);
      nv2 = s ? v2 : o1; ni2 = s ? i2 : oi1;
    } else {
      nv1 = o1; ni1 = oi1;
      const bool s = (o2 > v1) || (o2 == v1 && oi2 < i1);
      nv2 = s ? o2 : v1; ni2 = s ? oi2 : i1;
    }
    v1 = nv1; i1 = ni1; v2 = nv2; i2 = ni2;
  }
  if (lane == 0) { t2a[rowg] = i1; t2b[rowg] = i2; }
}

// ---------------------------------------------------------------------------
// Kernel 3 (fused graph): build sparse CSR (per-column edge lists) in LDS,
// run the pruning fixpoint in LDS, compute deg, top-144, export CSR + gidx.
// One block (288 threads) per batch. Edge (i,j): i!=j, j in top2(i) or
// i in top2(j); w = adj[i,j]. Mask invariant: active == (w != 0); pruning
// zeroes w (== Wsg * m since Wsg fixed). Column sums ascending-i == dense
// ascending-i sum (0.0f adds exact), deg = count(w!=0) == mask count.
// Termination: edges only ever zeroed (monotone) -> <= MAXE iterations.
// ---------------------------------------------------------------------------
__global__ __launch_bounds__(SSZ) void k_graph(const float* __restrict__ attn,
                                               const int* __restrict__ order,
                                               const int* __restrict__ t2a,
                                               const int* __restrict__ t2b,
                                               int* __restrict__ gidx,
                                               int* __restrict__ cs_g,
                                               int* __restrict__ eidx_g,
                                               float* __restrict__ ew_g) {
  __shared__ unsigned colbits[SSZ * 9];   // column-major bitmask: col j, bit i
  __shared__ int scan[SSZ];
  __shared__ int col_start[SSZ + 1];
  __shared__ int eidx[MAXE];
  __shared__ float ew[MAXE];
  __shared__ float avg[SSZ];
  __shared__ int degc[SSZ];
  __shared__ int s_changed;
  const int b = blockIdx.x;
  const int t = threadIdx.x;              // == column j and == row i (dual use)

  for (int k = t; k < SSZ * 9; k += SSZ) colbits[k] = 0;
  __syncthreads();

  // set bits: (t -> a1), (t -> a2) and transposes
  const int rb = b * SSZ;
  const int a1 = t2a[rb + t], a2 = t2b[rb + t];
  atomicOr(&colbits[a1 * 9 + (t >> 5)], 1u << (t & 31));
  atomicOr(&colbits[a2 * 9 + (t >> 5)], 1u << (t & 31));
  atomicOr(&colbits[t * 9 + (a1 >> 5)], 1u << (a1 & 31));
  atomicOr(&colbits[t * 9 + (a2 >> 5)], 1u << (a2 & 31));
  __syncthreads();

  // per-column count -> prefix sum -> col_start
  int cnt = 0;
  #pragma unroll
  for (int k = 0; k < 9; ++k) cnt += __popc(colbits[t * 9 + k]);
  scan[t] = cnt;
  __syncthreads();
  for (int off = 1; off < SSZ; off <<= 1) {
    const int v = (t >= off) ? scan[t - off] : 0;
    __syncthreads();
    scan[t] += v;
    __syncthreads();
  }
  if (t == 0) col_start[0] = 0;
  col_start[t + 1] = scan[t];
  __syncthreads();

  // fill entries of column t, ascending i; gather w from attention
  {
    const int* ordb = order + b * PTOK + DENS;
    const float* ab = attn + (size_t)b * AB_STRIDE;
    const int cj = ordb[t];
    int p = col_start[t];
    #pragma unroll
    for (int k = 0; k < 9; ++k) {
      unsigned m = colbits[t * 9 + k];
      while (m) {
        const int bit = __ffs(m) - 1; m &= m - 1;
        const int i = k * 32 + bit;
        const float w = (i == t) ? 0.0f
                                 : ab[(size_t)(1 + ordb[i]) * PTOK + cj];
        eidx[p] = i; ew[p] = w; ++p;
      }
    }
  }
  __syncthreads();

  // fixpoint: avg per column, prune edge (i,j=t) unless avg[j] > avg[i]
  for (;;) {
    if (t == 0) s_changed = 0;            // before barrier; sets come after it
    {
      const int s0 = col_start[t], s1 = col_start[t + 1];
      float ss = 0.0f; int dd = 0;
      for (int p = s0; p < s1; ++p) {
        const float w = ew[p];
        ss += w; dd += (w != 0.0f) ? 1 : 0;
      }
      degc[t] = dd;
      avg[t] = (dd > 0) ? (ss / (float)dd) : 0.0f;
    }
    __syncthreads();
    {
      const int s0 = col_start[t], s1 = col_start[t + 1];
      int local = 0;
      const float aj = avg[t];
      for (int p = s0; p < s1; ++p) {
        if (ew[p] != 0.0f && !(aj > avg[eidx[p]])) { ew[p] = 0.0f; local = 1; }
      }
      if (local) s_changed = 1;           // benign race: all writers store 1
    }
    __syncthreads();
    const int ch = s_changed;
    __syncthreads();                      // reads complete before next reset
    if (ch == 0) break;                   // degc holds final deg (no-op pass)
  }

  // top-144 of deg: rank by (deg desc, index asc) — exact integer compares
  {
    const int dj = degc[t];
    int rank = 0;
    for (int j2 = 0; j2 < SSZ; ++j2) {
      const int d2 = degc[j2];
      rank += ((d2 > dj) || (d2 == dj && j2 < t)) ? 1 : 0;
    }
    if (rank < GSZ) gidx[b * GSZ + rank] = t;
  }

  // export CSR for k_out_tokens
  for (int k = t; k < SSZ + 1; k += SSZ) cs_g[b * (SSZ + 1) + k] = col_start[k];
  const int E = col_start[SSZ];           // E <= MAXE by construction
  for (int k = t; k < E; k += SSZ) {
    eidx_g[b * MAXE + k] = eidx[k];
    ew_g[b * MAXE + k] = ew[k];
  }
}

// ---------------------------------------------------------------------------
// Kernel 4: out_tokens [64,433,768]. One block per (b,row); 192 thr x float4.
// rows 289..432: skip_embs[gidx] = sum_i W[i,j]*x_i + x_j via sparse column.
// ---------------------------------------------------------------------------
__global__ __launch_bounds__(192) void k_out_tokens(const float* __restrict__ tk,
                                                    const int* __restrict__ order,
                                                    const int* __restrict__ gidx,
                                                    const int* __restrict__ cs_g,
                                                    const int* __restrict__ eidx_g,
                                                    const float* __restrict__ ew_g,
                                                    float* __restrict__ out) {
  const int r = blockIdx.x;   // 0..432
  const int b = blockIdx.y;
  const int t = threadIdx.x;  // 0..191 -> float4
  const float* tkb = tk + (size_t)b * TK_BSTRIDE;
  float4 res;
  if (r == 0) {
    res = ((const float4*)tkb)[t];
  } else if (r <= DENS) {
    const int srow = 1 + order[b * PTOK + (r - 1)];
    res = ((const float4*)(tkb + (size_t)srow * DIM))[t];
  } else {
    const int j = gidx[b * GSZ + (r - (DENS + 1))];
    const int* ordb = order + b * PTOK + DENS;
    const int s0 = cs_g[b * (SSZ + 1) + j];
    const int s1 = cs_g[b * (SSZ + 1) + j + 1];
    // issue the residual row load first: overlaps with the sparse loop
    const float4 xj = ((const float4*)(tkb + (size_t)(1 + ordb[j]) * DIM))[t];
    float4 acc = make_float4(0.f, 0.f, 0.f, 0.f);
    for (int p = s0; p < s1; ++p) {        // ascending i: deterministic
      const float w = ew_g[b * MAXE + p];  // wave-uniform load
      if (w != 0.0f) {
        const int i = eidx_g[b * MAXE + p];
        const float4 xv = ((const float4*)(tkb + (size_t)(1 + ordb[i]) * DIM))[t];
        acc.x += w * xv.x; acc.y += w * xv.y;
        acc.z += w * xv.z; acc.w += w * xv.w;
      }
    }
    res = make_float4(acc.x + xj.x, acc.y + xj.y, acc.z + xj.z, acc.w + xj.w);
  }
  ((float4*)(out + ((size_t)b * OUT_ROWS + r) * DIM))[t] = res;
}

// ---------------------------------------------------------------------------
// Kernel 5: R [64,433,432]. Stage the (single) source attention row in LDS
// (coalesced), then permuted column gather from LDS instead of scattered
// global loads. R[b,r,c] = attention[b, srcrow(arow(r)), order[b, acol(c)]]
// ---------------------------------------------------------------------------
__global__ __launch_bounds__(PTOK) void k_R(const float* __restrict__ attn,
                                            const int* __restrict__ order,
                                            const int* __restrict__ gidx,
                                            float* __restrict__ outR) {
  __shared__ float rowbuf[PTOK];
  const int r = blockIdx.x;   // 0..432
  const int b = blockIdx.y;
  const int t = threadIdx.x;  // 0..575
  const int arow = (r <= DENS) ? r : (DENS + 1) + gidx[b * GSZ + (r - (DENS + 1))];
  const int srcrow = (arow == 0) ? 0 : 1 + order[b * PTOK + (arow - 1)];
  rowbuf[t] = attn[(size_t)b * AB_STRIDE + (size_t)srcrow * PTOK + t];
  __syncthreads();
  if (t < R_COLS) {
    const int acol = (t < DENS) ? t : DENS + gidx[b * GSZ + (t - DENS)];
    outR[((size_t)b * OUT_ROWS + r) * R_COLS + t] = rowbuf[order[b * PTOK + acol]];
  }
}

// ---------------------------------------------------------------------------
extern "C" void kernel_launch(void* const* d_in, const int* in_sizes, int n_in,
                              void* d_out, int out_size, void* d_ws, size_t ws_size,
                              hipStream_t stream) {
  if (ws_size < WS_NEEDED) return;  // defensive: never scribble past d_ws

  const float* tk   = (const float*)d_in[0];
  const float* attn = (const float*)d_in[1];
  float* out = (float*)d_out;

  // ws layout (~1 MB total, all fully rewritten every launch):
  //   order [64][576] i32 @ 0        (147456)
  //   t2a   [64][288] i32 @ 147456   ( 73728)
  //   t2b   [64][288] i32 @ 221184   ( 73728)
  //   gidx  [64][144] i32 @ 294912   ( 36864)
  //   cs    [64][289] i32 @ 331776   ( 73984)
  //   eidx  [64][1152]i32 @ 405760   (294912)
  //   ew    [64][1152]f32 @ 700672   (294912)  -> end 995584
  char* ws = (char*)d_ws;
  int*   order = (int*)(ws);
  int*   t2a   = (int*)(ws + 147456);
  int*   t2b   = (int*)(ws + 221184);
  int*   gidx  = (int*)(ws + 294912);
  int*   cs    = (int*)(ws + 331776);
  int*   eidx  = (int*)(ws + 405760);
  float* ew    = (float*)(ws + 700672);

  k_sort<<<BATCH, PTOK, 0, stream>>>(attn, order);
  k_top2<<<(BATCH * SSZ) / 4, 256, 0, stream>>>(attn, order, t2a, t2b);
  k_graph<<<BATCH, SSZ, 0, stream>>>(attn, order, t2a, t2b, gidx, cs, eidx, ew);
  k_out_tokens<<<dim3(OUT_ROWS, BATCH), 192, 0, stream>>>(tk, order, gidx,
                                                          cs, eidx, ew, out);
  k_R<<<dim3(OUT_ROWS, BATCH), PTOK, 0, stream>>>(attn, order, gidx,
                                                  out + OUT_TOK_TOTAL);
}